// Round 1
// baseline (525.757 us; speedup 1.0000x reference)
//
#include <hip/hip_runtime.h>
#include <hip/hip_bf16.h>
#include <math.h>

#define MDIM  128
#define FEAT  8256      // 128*129/2 (elements == bytes in fp8)
#define HID   1651
#define HIDP  1664      // 13*128, zero-padded
#define BATCH 4096
#define BK    64
#define KT_TOTAL 129    // FEAT / BK
#define NZ    2
#define KT_PER 64       // z=0: 64 iters, z=1: 65 iters
#define W1SCALE 8192.0f
#define W1INV   (1.0f / 8192.0f)

using f32x4  = __attribute__((ext_vector_type(4))) float;
using f32x16 = __attribute__((ext_vector_type(16))) float;
using i32x4  = __attribute__((ext_vector_type(4))) int;
using i32x8  = __attribute__((ext_vector_type(8))) int;
using bf16x8 = __attribute__((ext_vector_type(8))) __bf16;
typedef long long i64;

__device__ __forceinline__ void gload_lds16(const void* g, void* l) {
    __builtin_amdgcn_global_load_lds(
        (const __attribute__((address_space(1))) void*)g,
        (__attribute__((address_space(3))) void*)l,
        16, 0, 0);
}

__device__ __forceinline__ int row_off(int i) { return (i * (257 - i)) >> 1; }

// pack 8 floats -> 8 fp8 e4m3 bytes (two ints)
__device__ __forceinline__ void pack8_fp8(const float* f, int* o) {
    int lo = __builtin_amdgcn_cvt_pk_fp8_f32(f[0], f[1], 0, false);
    lo     = __builtin_amdgcn_cvt_pk_fp8_f32(f[2], f[3], lo, true);
    int hi = __builtin_amdgcn_cvt_pk_fp8_f32(f[4], f[5], 0, false);
    hi     = __builtin_amdgcn_cvt_pk_fp8_f32(f[6], f[7], hi, true);
    o[0] = lo; o[1] = hi;
}

// ---------------------------------------------------------------------------
// Kernel 1 (fused prep): blocks [0, BATCH) gather triu(sim) -> X fp8;
// blocks [BATCH, BATCH+5*HIDP) convert W1*8192 -> fp8 [HIDP, FEAT] (rows >=
// HID zeroed). Independent work, one dispatch: saves a launch + tail.
// ---------------------------------------------------------------------------
__global__ void __launch_bounds__(256)
prep_kernel(const float* __restrict__ sim, const float* __restrict__ W1,
            char* __restrict__ X, char* __restrict__ W1p) {
    const int t = threadIdx.x;
    if (blockIdx.x < BATCH) {
        // ---- pack X path ----
        const int b = blockIdx.x;
        const float* srow = sim + ((i64)b << 14);
        char* dst = X + (i64)b * FEAT;
#pragma unroll
        for (int it = 0; it < 5; ++it) {
            const int w = it * 256 + t;
            if (w < FEAT / 8) {
                const int f0 = w * 8;
                int i = (int)((257.0f - sqrtf(66049.0f - 8.0f * (float)f0)) * 0.5f);
                i = i < 0 ? 0 : (i > 127 ? 127 : i);
                while (i < 127 && row_off(i + 1) <= f0) ++i;
                while (i > 0 && row_off(i) > f0) --i;
                int j = i + (f0 - row_off(i));
                float v[8];
#pragma unroll
                for (int e = 0; e < 8; ++e) {
                    if (j > 127) { ++i; j = i; }
                    v[e] = srow[i * MDIM + j];
                    ++j;
                }
                int o[2];
                pack8_fp8(v, o);
                *(int2*)(dst + f0) = make_int2(o[0], o[1]);
            }
        }
    } else {
        // ---- convert W1 path ----
        const int c  = blockIdx.x - BATCH;   // 0 .. 5*HIDP-1
        const int wb = c % 5;
        const int n  = c / 5;
        const int w  = wb * 256 + t;
        if (w >= FEAT / 8) return;
        const int f0 = w * 8;
        int o[2];
        if (n < HID) {
            const float* src = W1 + (i64)n * FEAT + f0;
            const f32x4 a = *(const f32x4*)src;
            const f32x4 d = *(const f32x4*)(src + 4);
            float v[8];
#pragma unroll
            for (int e = 0; e < 4; ++e) {
                v[e]     = a[e] * W1SCALE;
                v[e + 4] = d[e] * W1SCALE;
            }
            pack8_fp8(v, o);
        } else {
            o[0] = 0; o[1] = 0;
        }
        *(int2*)(W1p + (i64)n * FEAT + f0) = make_int2(o[0], o[1]);
    }
}

// ---------------------------------------------------------------------------
// Kernel 2: split-K (NZ=2) MX-scaled fp8 GEMM, 128x128 tile, BK=64.
// v_mfma_scale_f32_32x32x64_f8f6f4 with unit scales (0x7F = 2^0) -> 2x the
// non-scaled fp8 rate, numerics identical to plain e4m3 MFMA.
//
// LDS layout is K-MAJOR at 16B-chunk granularity:
//   phys(row, chunk) = chunk*2048 + row*16   (chunk 0..3 of the 64B K-step)
// -> each lane's 32B fragment = two conflict-free ds_read_b128 (32 consecutive
//    rows x 16B = uniform bank usage). global_load_lds writes linearly
//    (base + lane*16); we pick each lane's GLOBAL source to realize the
//    layout: thread t=(wave w, lane l), issue s stages
//    row=(w&1)*64+l, chunk=2s+(w>>1).
// Double-buffered: issue next K-step's staging BEFORE current ds_read+MFMA,
// ONE barrier per K-step (staging latency hides under compute).
//
// Within-K slot permutations of the assumed A/B fragment layout cancel (A and
// B are addressed identically), so correctness only depends on m/n = lane&31
// and the HW-verified 32x32 C/D mapping.
// ---------------------------------------------------------------------------
__global__ void __launch_bounds__(256, 4)
gemm_split_kernel(const char* __restrict__ X,
                  const char* __restrict__ W1p,
                  __hip_bfloat16* __restrict__ Cz) {
    __shared__ __align__(16) char lds_a[2 * 8192];   // 16 KB (double buffer)
    __shared__ __align__(16) char lds_b[2 * 8192];   // 16 KB

    const int t    = threadIdx.x;
    const int w    = t >> 6;
    const int l    = t & 63;
    const int bm   = blockIdx.x;
    const int bn   = blockIdx.y;
    const int z    = blockIdx.z;
    const int wm   = w >> 1;          // wave row (0..1) -> 64 output rows
    const int wn   = w & 1;           // wave col (0..1) -> 64 output cols
    const int lm   = l & 31;
    const int c0   = (l >> 5) << 1;   // chunk base for this lane's K-half

    f32x16 acc[2][2];
#pragma unroll
    for (int r = 0; r < 16; ++r) {
        acc[0][0][r] = 0.f; acc[0][1][r] = 0.f;
        acc[1][0][r] = 0.f; acc[1][1][r] = 0.f;
    }

    const int kt0 = z * KT_PER;
    const int nkt = (z == NZ - 1) ? (KT_TOTAL - KT_PER * (NZ - 1)) : KT_PER;

    // staging roles: thread t covers row (w&1)*64+l, chunks {(w>>1), (w>>1)+2}
    const int stR = ((w & 1) << 6) + l;
    const int stC = w >> 1;
    const char* gA0 = X + (i64)(bm * 128 + stR) * FEAT + kt0 * BK + stC * 16;
    const char* gB0 = W1p + (i64)(bn * 128 + stR) * FEAT + kt0 * BK + stC * 16;
    char* lA = lds_a + w * 1024;      // wave-uniform LDS dest base
    char* lB = lds_b + w * 1024;

#define STAGE(bufoff, kidx) do {                                   \
        const char* _ga = gA0 + (i64)(kidx) * BK;                  \
        const char* _gb = gB0 + (i64)(kidx) * BK;                  \
        gload_lds16(_ga,      lA + (bufoff));                      \
        gload_lds16(_ga + 32, lA + (bufoff) + 4096);               \
        gload_lds16(_gb,      lB + (bufoff));                      \
        gload_lds16(_gb + 32, lB + (bufoff) + 4096);               \
    } while (0)

    STAGE(0, 0);
    __syncthreads();

    int cur = 0;
    for (int kt = 0; kt < nkt; ++kt) {
        const int nxt = cur ^ 1;
        if (kt + 1 < nkt) STAGE(nxt * 8192, kt + 1);  // prefetch next K-step

        const char* pa = lds_a + cur * 8192 + c0 * 2048 + (wm * 64 + lm) * 16;
        const char* pb = lds_b + cur * 8192 + c0 * 2048 + (wn * 64 + lm) * 16;
        const i32x4 a0l = *(const i32x4*)(pa);
        const i32x4 a0h = *(const i32x4*)(pa + 2048);
        const i32x4 a1l = *(const i32x4*)(pa + 512);
        const i32x4 a1h = *(const i32x4*)(pa + 512 + 2048);
        const i32x4 b0l = *(const i32x4*)(pb);
        const i32x4 b0h = *(const i32x4*)(pb + 2048);
        const i32x4 b1l = *(const i32x4*)(pb + 512);
        const i32x4 b1h = *(const i32x4*)(pb + 512 + 2048);
        const i32x8 A0 = __builtin_shufflevector(a0l, a0h, 0, 1, 2, 3, 4, 5, 6, 7);
        const i32x8 A1 = __builtin_shufflevector(a1l, a1h, 0, 1, 2, 3, 4, 5, 6, 7);
        const i32x8 B0 = __builtin_shufflevector(b0l, b0h, 0, 1, 2, 3, 4, 5, 6, 7);
        const i32x8 B1 = __builtin_shufflevector(b1l, b1h, 0, 1, 2, 3, 4, 5, 6, 7);

        // fmt 0 = OCP fp8 e4m3; scales 0x7F = 2^0 (unit) in every byte so
        // opsel is immaterial.
        acc[0][0] = __builtin_amdgcn_mfma_scale_f32_32x32x64_f8f6f4(
            A0, B0, acc[0][0], 0, 0, 0, 0x7F7F7F7F, 0, 0x7F7F7F7F);
        acc[0][1] = __builtin_amdgcn_mfma_scale_f32_32x32x64_f8f6f4(
            A0, B1, acc[0][1], 0, 0, 0, 0x7F7F7F7F, 0, 0x7F7F7F7F);
        acc[1][0] = __builtin_amdgcn_mfma_scale_f32_32x32x64_f8f6f4(
            A1, B0, acc[1][0], 0, 0, 0, 0x7F7F7F7F, 0, 0x7F7F7F7F);
        acc[1][1] = __builtin_amdgcn_mfma_scale_f32_32x32x64_f8f6f4(
            A1, B1, acc[1][1], 0, 0, 0, 0x7F7F7F7F, 0, 0x7F7F7F7F);

        __syncthreads();   // drains this iter's stage loads; releases buffers
        cur = nxt;
    }
#undef STAGE

    // 32x32 C/D mapping: col = lane&31, row = (reg&3) + 8*(reg>>2) + 4*(lane>>5)
    __hip_bfloat16* cz = Cz + ((i64)z * BATCH + bm * 128) * HIDP
                            + bn * 128 + wn * 64;
#pragma unroll
    for (int rb = 0; rb < 2; ++rb)
#pragma unroll
        for (int cb = 0; cb < 2; ++cb) {
#pragma unroll
            for (int reg = 0; reg < 16; ++reg) {
                const int row = (reg & 3) + ((reg >> 2) << 3) + ((l >> 5) << 2);
                const int ml  = wm * 64 + rb * 32 + row;
                cz[(i64)ml * HIDP + cb * 32 + lm] =
                    __float2bfloat16(acc[rb][cb][reg]);
            }
        }
}

// ---------------------------------------------------------------------------
// Kernel 3: out[b] = sigmoid(b2 + sum_n relu((Cz0+Cz1)*W1INV + b1[n]) * W2[n])
// ---------------------------------------------------------------------------
__global__ void __launch_bounds__(256)
epilogue_kernel(const __hip_bfloat16* __restrict__ Cz,
                const float* __restrict__ b1,
                const float* __restrict__ W2,
                const float* __restrict__ b2,
                float* __restrict__ out) {
    const int b = blockIdx.x;
    const int t = threadIdx.x;
    float sum = 0.0f;
    const bf16x8* r0 = (const bf16x8*)(Cz + (i64)b * HIDP);
    const bf16x8* r1 = (const bf16x8*)(Cz + ((i64)BATCH + b) * HIDP);
    if (t < HIDP / 8) {   // 208 active threads, one pass
        const bf16x8 a = r0[t];
        const bf16x8 c = r1[t];
#pragma unroll
        for (int e = 0; e < 8; ++e) {
            const int n = t * 8 + e;
            if (n < HID) {
                const float v = ((float)a[e] + (float)c[e]) * W1INV + b1[n];
                sum += fmaxf(v, 0.0f) * W2[n];
            }
        }
    }
    sum += __shfl_xor(sum, 1);
    sum += __shfl_xor(sum, 2);
    sum += __shfl_xor(sum, 4);
    sum += __shfl_xor(sum, 8);
    sum += __shfl_xor(sum, 16);
    sum += __shfl_xor(sum, 32);
    __shared__ float wsum[4];
    if ((t & 63) == 0) wsum[t >> 6] = sum;
    __syncthreads();
    if (t == 0) {
        const float s = wsum[0] + wsum[1] + wsum[2] + wsum[3];
        out[b] = 1.0f / (1.0f + expf(-(s + b2[0])));
    }
}

extern "C" void kernel_launch(void* const* d_in, const int* in_sizes, int n_in,
                              void* d_out, int out_size, void* d_ws, size_t ws_size,
                              hipStream_t stream) {
    const float* sim = (const float*)d_in[0];
    const float* W1  = (const float*)d_in[1];
    const float* b1  = (const float*)d_in[2];
    const float* W2  = (const float*)d_in[3];
    const float* b2  = (const float*)d_in[4];
    float* out = (float*)d_out;

    char* ws = (char*)d_ws;
    const i64 X_OFF   = 0;                       // 33,816,576 B
    const i64 W1P_OFF = (i64)BATCH * FEAT;       // fp8: elems == bytes
    const i64 CZ_OFF  = W1P_OFF + (i64)HIDP * FEAT;  // +13,737,984
    // Cz: NZ*BATCH*HIDP*2 = 27,262,976 B; total 74,817,536 < proven ws bound
    char*           Xf8  = ws + X_OFF;
    char*           W1f8 = ws + W1P_OFF;
    __hip_bfloat16* Cz   = (__hip_bfloat16*)(ws + CZ_OFF);

    prep_kernel<<<BATCH + 5 * HIDP, 256, 0, stream>>>(sim, W1, Xf8, W1f8);
    {
        dim3 grid(BATCH / 128, HIDP / 128, NZ);        // (32, 13, 2)
        gemm_split_kernel<<<grid, 256, 0, stream>>>(Xf8, W1f8, Cz);
    }
    epilogue_kernel<<<BATCH, 256, 0, stream>>>(Cz, b1, W2, b2, out);
}